// Round 1
// baseline (228.743 us; speedup 1.0000x reference)
//
#include <hip/hip_runtime.h>

// Haar DWT along axis 1 of (8, 4096, 1024) fp32.
// cA[b,j,c] = (x[b,2j,c] + x[b,2j+1,c]) * k,  cD = (x_even - x_odd) * k
// d_out = [cA flat | cD flat].
//
// Pure streaming (268 MB, zero reuse). 4 pair-rows per block, float4 lanes.
// Loads: PLAIN cached (NT load hint removed — m13's 6.29 TB/s copy ceiling
// was measured with cached loads; NT on the read path has no measured win).
// All 8 loads hoisted ahead of compute/store so vmcnt drains never
// interleave with load issue. Stores stay nontemporal (streaming output,
// don't allocate in L2).

#define NPAIR (8 * 2048)        // total pair-rows
#define ROWS_PER_BLOCK 4
#define NPAIR_VEC (NPAIR * 256) // vec4 elements per output half

typedef float f4 __attribute__((ext_vector_type(4)));

__global__ __launch_bounds__(256) void dwt_haar_kernel(
    const f4* __restrict__ x,
    f4* __restrict__ cA,
    f4* __restrict__ cD)
{
    const float k = 0.7071067811865476f;
    const int t = threadIdx.x;                   // vec4 column 0..255
    const int r0 = blockIdx.x * ROWS_PER_BLOCK;  // first pair-row of block

    // Preload phase: issue all 8 global_load_dwordx4 back-to-back.
    // 8 x f4 = 32 data VGPRs; total ~48 VGPR -> full 32 waves/CU occupancy.
    f4 a[ROWS_PER_BLOCK], b[ROWS_PER_BLOCK];
#pragma unroll
    for (int j = 0; j < ROWS_PER_BLOCK; ++j) {
        const int e = (r0 + j) * 512 + t;        // even input row, vec4 units
        a[j] = x[e];
        b[j] = x[e + 256];
    }

    // Compute + store phase.
#pragma unroll
    for (int j = 0; j < ROWS_PER_BLOCK; ++j) {
        const f4 s = (a[j] + b[j]) * k;
        const f4 d = (a[j] - b[j]) * k;
        const int o = (r0 + j) * 256 + t;
        __builtin_nontemporal_store(s, &cA[o]);
        __builtin_nontemporal_store(d, &cD[o]);
    }
}

extern "C" void kernel_launch(void* const* d_in, const int* in_sizes, int n_in,
                              void* d_out, int out_size, void* d_ws, size_t ws_size,
                              hipStream_t stream)
{
    const f4* x = (const f4*)d_in[0];
    f4* cA = (f4*)d_out;
    f4* cD = cA + NPAIR_VEC;

    const int nblocks = NPAIR / ROWS_PER_BLOCK;  // 4096
    dwt_haar_kernel<<<nblocks, 256, 0, stream>>>(x, cA, cD);
}

// Round 2
// 219.319 us; speedup vs baseline: 1.0430x; 1.0430x over previous
//
#include <hip/hip_runtime.h>

// Haar DWT along axis 1 of (8, 4096, 1024) fp32.
// cA[b,j,c] = (x[b,2j,c] + x[b,2j+1,c]) * k,  cD = (x_even - x_odd) * k
// d_out = [cA flat | cD flat].
//
// Pure streaming (268 MB, zero reuse). Lessons measured on this problem:
//  - NT loads > cached loads for the once-read input stream (round-1 A/B:
//    cached loads = 80.5 us / 2.5 TB/s despite 50% L3 hits; NT version was
//    faster while moving MORE HBM bytes -> cache-allocate path throttles).
//  - NT stores for the output (never re-read, don't allocate).
// Structure: 8 pair-rows per block (grid = 2048 = 8 blocks/CU exactly),
// all 16 loads issued back-to-back before any compute/store so each wave
// has 256 B/lane in flight before the first vmcnt wait; stores are
// fire-and-forget and never precede a dependent load wait.

#define NPAIR (8 * 2048)        // total pair-rows
#define ROWS_PER_BLOCK 8
#define NPAIR_VEC (NPAIR * 256) // vec4 elements per output half

typedef float f4 __attribute__((ext_vector_type(4)));

__global__ __launch_bounds__(256) void dwt_haar_kernel(
    const f4* __restrict__ x,
    f4* __restrict__ cA,
    f4* __restrict__ cD)
{
    const float k = 0.7071067811865476f;
    const int t = threadIdx.x;                   // vec4 column 0..255
    const int r0 = blockIdx.x * ROWS_PER_BLOCK;  // first pair-row of block

    // Preload: 16 global_load_dwordx4 nt, issued back-to-back.
    // 16 x f4 = 64 data VGPRs (+addressing ~80 total) -> ~6 waves/SIMD.
    f4 a[ROWS_PER_BLOCK], b[ROWS_PER_BLOCK];
#pragma unroll
    for (int j = 0; j < ROWS_PER_BLOCK; ++j) {
        const int e = (r0 + j) * 512 + t;        // even input row, vec4 units
        a[j] = __builtin_nontemporal_load(&x[e]);
        b[j] = __builtin_nontemporal_load(&x[e + 256]);
    }

    // Compute + store, in load-completion order.
#pragma unroll
    for (int j = 0; j < ROWS_PER_BLOCK; ++j) {
        const f4 s = (a[j] + b[j]) * k;
        const f4 d = (a[j] - b[j]) * k;
        const int o = (r0 + j) * 256 + t;
        __builtin_nontemporal_store(s, &cA[o]);
        __builtin_nontemporal_store(d, &cD[o]);
    }
}

extern "C" void kernel_launch(void* const* d_in, const int* in_sizes, int n_in,
                              void* d_out, int out_size, void* d_ws, size_t ws_size,
                              hipStream_t stream)
{
    const f4* x = (const f4*)d_in[0];
    f4* cA = (f4*)d_out;
    f4* cD = cA + NPAIR_VEC;

    const int nblocks = NPAIR / ROWS_PER_BLOCK;  // 2048 = 8 blocks/CU
    dwt_haar_kernel<<<nblocks, 256, 0, stream>>>(x, cA, cD);
}